// Round 6
// baseline (146.437 us; speedup 1.0000x reference)
//
#include <hip/hip_runtime.h>
#include <math.h>

#define DD 160
#define HH 160
#define WW 160
#define NB 2
#define NEL (NB*DD*HH*WW)   // 8,192,000 voxels

#define XT 32               // x outputs per block
#define YT 32               // y outputs per block
#define NY 4                // y outputs per thread
#define ZC 16               // z outputs per block
#define NTHR 256
#define NZCH (DD/ZC)        // 10
#define GX (WW/XT)          // 5
#define GY (HH/YT)          // 5
#define NPART (GX*GY*NB*NZCH)  // 500 blocks x 8 waves = 4000 waves

#define HR 38               // halo rows (32 + 6)
#define NJOB (HR*8)         // 304 x-conv jobs
#define CP 35               // c4 physical pitch in float4 (32 + swizzle)

typedef float v2f __attribute__((ext_vector_type(2)));

struct G7 { float g[7]; };

// Fully fused separable 3D SSIM, v5:
//  * v2f (ext_vector_type) packed channel-pairs -> v_pk_fma_f32 on gfx950.
//  * x-conv from global (3 aligned float4/array), STREAMED into 4 running
//    accumulators (low live-register count), written as float4 to LDS.
//  * 4 y-outputs per thread: C-phase streams 10 rows for 8 column-values.
//  * c4 column swizzle pc = c + (c>>3): conflict-free b128 LDS.
//  * double-buffered c4 -> one barrier per z-slice.
//  * z-conv via v2f register rings; SSIM consumed in-register.
__global__ __launch_bounds__(NTHR, 4) void ssim_fused(
        const float* __restrict__ p, const float* __restrict__ t,
        float* __restrict__ partial, G7 gw) {
    const int tid = threadIdx.x;
    const int tx  = tid & 31;            // x output column (phase C)
    const int tyo = tid >> 5;            // 0..7, owns y = 4*tyo .. 4*tyo+3
    const int x0 = blockIdx.x * XT;
    const int y0 = blockIdx.y * YT;
    const int n  = blockIdx.z / NZCH;
    const int zs = (blockIdx.z % NZCH) * ZC;

    __shared__ float4 c4[2][HR][CP];

    // z rings: [y-out][slot], slot5 freshest
    v2f r01[NY][6], r23[NY][6];
#pragma unroll
    for (int yo = 0; yo < NY; ++yo)
#pragma unroll
        for (int j = 0; j < 6; ++j) {
            r01[yo][j] = (v2f)(0.f);
            r23[yo][j] = (v2f)(0.f);
        }

    const float C1v = 1e-4f, C2v = 9e-4f;
    float ssum = 0.f;
    const int hw = HH * WW;
    const float* pv = p + (size_t)n * DD * hw;
    const float* tv = t + (size_t)n * DD * hw;

    // phase-B job decode: job = br*8 + bxg; two rounds (256 + 48)
    const int br0 = tid >> 3, bxg0 = tid & 7;
    const int br1 = (tid + NTHR) >> 3, bxg1 = tid & 7;
    const int pcr = tx + (tx >> 3);      // C-phase swizzled column

    for (int s = zs - 3; s < zs + ZC + 3; ++s) {
        const int par = s & 1;

        const bool valid = (s >= 0) && (s < DD);   // block-uniform
        v2f m01[NY], m23[NY];
        if (valid) {
            const float* pz = pv + (size_t)s * hw;
            const float* tz = tv + (size_t)s * hw;

            // ---- B: x-conv from global, streamed accumulation ----
#pragma unroll
            for (int rnd = 0; rnd < 2; ++rnd) {
                const int br  = rnd ? br1 : br0;
                const int bxg = rnd ? bxg1 : bxg0;
                if (rnd == 0 || tid < NJOB - NTHR) {
                    const int gy = y0 + br - 3;
                    const bool rowok = (unsigned)gy < (unsigned)HH;
                    const float* prow = pz + gy * WW;
                    const float* trow = tz + gy * WW;
                    const int cbase = x0 + 4 * bxg - 4;
                    v2f s01[4], s23[4];
#pragma unroll
                    for (int e = 0; e < 4; ++e) { s01[e] = (v2f)(0.f); s23[e] = (v2f)(0.f); }
#pragma unroll
                    for (int q = 0; q < 3; ++q) {
                        int c0 = cbase + 4 * q;
                        float4 a = make_float4(0.f, 0.f, 0.f, 0.f);
                        float4 b = a;
                        if (rowok && (unsigned)c0 < (unsigned)WW) {
                            a = *(const float4*)(prow + c0);
                            b = *(const float4*)(trow + c0);
                        }
                        const float af[4] = {a.x, a.y, a.z, a.w};
                        const float bf[4] = {b.x, b.y, b.z, b.w};
#pragma unroll
                        for (int j = 0; j < 4; ++j) {
                            const int i = 4 * q + j;     // loaded position 0..11
                            v2f pt; pt[0] = af[j]; pt[1] = bf[j];
                            v2f ud; ud[0] = af[j] + bf[j]; ud[1] = af[j] - bf[j];
                            v2f qu = ud * ud;
#pragma unroll
                            for (int e = 0; e < 4; ++e) {
                                const int k = i - e - 1;  // tap index
                                if (k >= 0 && k < 7) {
                                    s01[e] = gw.g[k] * pt + s01[e];
                                    s23[e] = gw.g[k] * qu + s23[e];
                                }
                            }
                        }
                    }
#pragma unroll
                    for (int e = 0; e < 4; ++e) {
                        int c = 4 * bxg + e;
                        c4[par][br][c + (c >> 3)] =
                            make_float4(s01[e][0], s01[e][1], s23[e][0], s23[e][1]);
                    }
                }
            }
            __syncthreads();   // block-uniform

            // ---- C: y-conv, stream 10 rows for 4 y-outputs ----
#pragma unroll
            for (int yo = 0; yo < NY; ++yo) { m01[yo] = (v2f)(0.f); m23[yo] = (v2f)(0.f); }
#pragma unroll
            for (int r10 = 0; r10 < 10; ++r10) {
                float4 v = c4[par][4 * tyo + r10][pcr];
                v2f v01; v01[0] = v.x; v01[1] = v.y;
                v2f v23; v23[0] = v.z; v23[1] = v.w;
#pragma unroll
                for (int yo = 0; yo < NY; ++yo) {
                    const int k = r10 - yo;
                    if (k >= 0 && k < 7) {
                        m01[yo] = gw.g[k] * v01 + m01[yo];
                        m23[yo] = gw.g[k] * v23 + m23[yo];
                    }
                }
            }
            // no trailing barrier: dbuf; WAR fenced by next slice's barrier.
        } else {
#pragma unroll
            for (int yo = 0; yo < NY; ++yo) { m01[yo] = (v2f)(0.f); m23[yo] = (v2f)(0.f); }
        }

        // ---- z rings: consume slot0, shift+FMA, refill ----
#pragma unroll
        for (int yo = 0; yo < NY; ++yo) {
            v2f v01 = m01[yo], v23 = m23[yo];
            v2f cons01 = gw.g[6] * v01 + r01[yo][0];
            v2f cons23 = gw.g[6] * v23 + r23[yo][0];
#pragma unroll
            for (int j = 0; j < 5; ++j) {
                r01[yo][j] = gw.g[5 - j] * v01 + r01[yo][j + 1];
                r23[yo][j] = gw.g[5 - j] * v23 + r23[yo][j + 1];
            }
            r01[yo][5] = gw.g[0] * v01;
            r23[yo][5] = gw.g[0] * v23;

            if (s >= zs + 3) {   // output z = s-3
                float mu1 = cons01[0], mu2 = cons01[1];
                float Eu  = cons23[0], Ew  = cons23[1];
                float mu12 = mu1 * mu2, mu1sq = mu1 * mu1, mu2sq = mu2 * mu2;
                float sumsq = 0.5f  * (Eu + Ew) - mu1sq - mu2sq; // s1+s2
                float s12   = 0.25f * (Eu - Ew) - mu12;          // sigma12
                float num = (2.f * mu12 + C1v) * (2.f * s12 + C2v);
                float den = (mu1sq + mu2sq + C1v) * (sumsq + C2v);
                ssum += num * __builtin_amdgcn_rcpf(den);
            }
        }
    }

    // ---- block reduction (8 waves) ----
#pragma unroll
    for (int off = 32; off > 0; off >>= 1)
        ssum += __shfl_down(ssum, off, 64);
    __shared__ float wsum[8];
    if ((tid & 63) == 0) wsum[tid >> 6] = ssum;
    __syncthreads();
    if (tid == 0) {
        float tot = 0.f;
#pragma unroll
        for (int w = 0; w < 8; ++w) tot += wsum[w];
        int bid = (blockIdx.z * GY + blockIdx.y) * GX + blockIdx.x;
        partial[bid] = tot;
    }
}

__global__ __launch_bounds__(256) void ssim_final(
        const float* __restrict__ partial, float* __restrict__ out) {
    float s = 0.f;
    for (int i = threadIdx.x; i < NPART; i += 256) s += partial[i];
#pragma unroll
    for (int off = 32; off > 0; off >>= 1)
        s += __shfl_down(s, off, 64);
    __shared__ float wsum[4];
    int lane = threadIdx.x & 63, wid = threadIdx.x >> 6;
    if (lane == 0) wsum[wid] = s;
    __syncthreads();
    if (threadIdx.x == 0) {
        float tot = wsum[0] + wsum[1] + wsum[2] + wsum[3];
        out[0] = 1.0f - tot / (float)NEL;
    }
}

extern "C" void kernel_launch(void* const* d_in, const int* in_sizes, int n_in,
                              void* d_out, int out_size, void* d_ws, size_t ws_size,
                              hipStream_t stream) {
    const float* p = (const float*)d_in[0];
    const float* t = (const float*)d_in[1];
    float* out = (float*)d_out;
    float* partial = (float*)d_ws;   // NPART floats

    G7 gw;
    {
        double s = 0.0, sig = 7.0 / 6.0;
        double g[7];
        for (int i = 0; i < 7; ++i) {
            double d = (double)i - 3.0;
            g[i] = exp(-d * d / (2.0 * sig * sig));
            s += g[i];
        }
        for (int i = 0; i < 7; ++i) gw.g[i] = (float)(g[i] / s);
    }

    dim3 grid(GX, GY, NB * NZCH);   // (5, 5, 20) = 500 blocks
    ssim_fused<<<grid, NTHR, 0, stream>>>(p, t, partial, gw);
    ssim_final<<<1, 256, 0, stream>>>(partial, out);
}

// Round 7
// 132.405 us; speedup vs baseline: 1.1060x; 1.1060x over previous
//
#include <hip/hip_runtime.h>
#include <math.h>

#define DD 160
#define HH 160
#define WW 160
#define NB 2
#define NEL (NB*DD*HH*WW)   // 8,192,000 voxels

#define XT 32               // x outputs per block
#define YT 16               // y outputs per block
#define ZC 16               // z outputs per block
#define NTHR 256
#define NZCH (DD/ZC)        // 10
#define GX (WW/XT)          // 5
#define GY (HH/YT)          // 10
#define NPART (GX*GY*NB*NZCH)  // 1000 blocks x 4 waves = 4000 waves

#define HR 22               // halo rows (16 + 6)
#define NJOB (HR*8)         // 176 x-conv jobs (< NTHR)
#define CP 35               // c4 physical pitch in float4 (32 + swizzle)

typedef float v2f __attribute__((ext_vector_type(2)));

struct G7 { float g[7]; };

// Fully fused separable 3D SSIM, v6 = R5 structure + v2f packed math:
//  * grid 1000 blocks x 4 waves (R6 taught: grid shape > per-thread reuse).
//  * x-conv jobs (176) load 3 aligned float4/array straight from global,
//    streamed into 4 running v2f accumulators -> v_pk_fma_f32.
//  * 4 channels packed as (p,t) and ((p+t)^2,(p-t)^2) v2f pairs.
//  * c4 column swizzle pc = c + (c>>3): conflict-free b128 LDS.
//  * double-buffered c4 -> one barrier per z-slice.
//  * z-conv via v2f register rings; SSIM consumed in-register.
__global__ __launch_bounds__(NTHR, 4) void ssim_fused(
        const float* __restrict__ p, const float* __restrict__ t,
        float* __restrict__ partial, G7 gw) {
    const int tid = threadIdx.x;
    const int tx  = tid & 31;            // x output column (phase C)
    const int tyo = tid >> 5;            // 0..7, owns y = 2tyo, 2tyo+1
    const int x0 = blockIdx.x * XT;
    const int y0 = blockIdx.y * YT;
    const int n  = blockIdx.z / NZCH;
    const int zs = (blockIdx.z % NZCH) * ZC;

    __shared__ float4 c4[2][HR][CP];

    // z rings: [y-out][slot], slot5 freshest
    v2f r01[2][6], r23[2][6];
#pragma unroll
    for (int yo = 0; yo < 2; ++yo)
#pragma unroll
        for (int j = 0; j < 6; ++j) {
            r01[yo][j] = (v2f)(0.f);
            r23[yo][j] = (v2f)(0.f);
        }

    const float C1v = 1e-4f, C2v = 9e-4f;
    float ssum = 0.f;
    const int hw = HH * WW;
    const float* pv = p + (size_t)n * DD * hw;
    const float* tv = t + (size_t)n * DD * hw;

    // phase-B job decode (tid < 176): row br, x-group bxg
    const int br = tid >> 3;             // 0..21
    const int bxg = tid & 7;             // 0..7
    const int bgy = y0 + br - 3;
    const bool browok = (unsigned)bgy < (unsigned)HH && tid < NJOB;
    const int cbase = x0 + 4 * bxg - 4;  // first loaded column (4-aligned)
    const int pcr = tx + (tx >> 3);      // C-phase swizzled column

    for (int s = zs - 3; s < zs + ZC + 3; ++s) {
        const int par = s & 1;
        v2f m01[2], m23[2];
#pragma unroll
        for (int yo = 0; yo < 2; ++yo) {
            m01[yo] = (v2f)(0.f);
            m23[yo] = (v2f)(0.f);
        }

        const bool valid = (s >= 0) && (s < DD);   // block-uniform
        if (valid) {
            // ---- B: x-conv from global, streamed v2f accumulation ----
            if (tid < NJOB) {
                const float* prow = pv + (size_t)s * hw + bgy * WW;
                const float* trow = tv + (size_t)s * hw + bgy * WW;
                v2f s01[4], s23[4];
#pragma unroll
                for (int e = 0; e < 4; ++e) { s01[e] = (v2f)(0.f); s23[e] = (v2f)(0.f); }
#pragma unroll
                for (int q = 0; q < 3; ++q) {
                    int c0 = cbase + 4 * q;
                    float4 a = make_float4(0.f, 0.f, 0.f, 0.f);
                    float4 b = a;
                    if (browok && (unsigned)c0 < (unsigned)WW) {
                        a = *(const float4*)(prow + c0);
                        b = *(const float4*)(trow + c0);
                    }
                    const float af[4] = {a.x, a.y, a.z, a.w};
                    const float bf[4] = {b.x, b.y, b.z, b.w};
#pragma unroll
                    for (int j = 0; j < 4; ++j) {
                        const int i = 4 * q + j;     // loaded position 0..11
                        v2f pt; pt[0] = af[j]; pt[1] = bf[j];
                        v2f ud; ud[0] = af[j] + bf[j]; ud[1] = af[j] - bf[j];
                        v2f qu = ud * ud;
#pragma unroll
                        for (int e = 0; e < 4; ++e) {
                            const int k = i - e - 1;  // tap index
                            if (k >= 0 && k < 7) {
                                s01[e] = gw.g[k] * pt + s01[e];
                                s23[e] = gw.g[k] * qu + s23[e];
                            }
                        }
                    }
                }
#pragma unroll
                for (int e = 0; e < 4; ++e) {
                    int c = 4 * bxg + e;
                    c4[par][br][c + (c >> 3)] =
                        make_float4(s01[e][0], s01[e][1], s23[e][0], s23[e][1]);
                }
            }
            __syncthreads();   // block-uniform (valid is uniform)

            // ---- C: y-conv, stream 8 rows for both y-outputs ----
#pragma unroll
            for (int r8 = 0; r8 < 8; ++r8) {
                float4 v = c4[par][2 * tyo + r8][pcr];
                v2f v01; v01[0] = v.x; v01[1] = v.y;
                v2f v23; v23[0] = v.z; v23[1] = v.w;
                if (r8 < 7) {
                    float w = gw.g[r8];
                    m01[0] = w * v01 + m01[0];
                    m23[0] = w * v23 + m23[0];
                }
                if (r8 > 0) {
                    float w = gw.g[r8 - 1];
                    m01[1] = w * v01 + m01[1];
                    m23[1] = w * v23 + m23[1];
                }
            }
            // no trailing barrier: dbuf; WAR fenced by next slice's barrier.
        }

        // ---- z rings: consume slot0, shift+FMA, refill ----
#pragma unroll
        for (int yo = 0; yo < 2; ++yo) {
            v2f v01 = m01[yo], v23 = m23[yo];
            v2f cons01 = gw.g[6] * v01 + r01[yo][0];
            v2f cons23 = gw.g[6] * v23 + r23[yo][0];
#pragma unroll
            for (int j = 0; j < 5; ++j) {
                r01[yo][j] = gw.g[5 - j] * v01 + r01[yo][j + 1];
                r23[yo][j] = gw.g[5 - j] * v23 + r23[yo][j + 1];
            }
            r01[yo][5] = gw.g[0] * v01;
            r23[yo][5] = gw.g[0] * v23;

            if (s >= zs + 3) {   // output z = s-3
                float mu1 = cons01[0], mu2 = cons01[1];
                float Eu  = cons23[0], Ew  = cons23[1];
                float mu12 = mu1 * mu2, mu1sq = mu1 * mu1, mu2sq = mu2 * mu2;
                float sumsq = 0.5f  * (Eu + Ew) - mu1sq - mu2sq; // s1+s2
                float s12   = 0.25f * (Eu - Ew) - mu12;          // sigma12
                float num = (2.f * mu12 + C1v) * (2.f * s12 + C2v);
                float den = (mu1sq + mu2sq + C1v) * (sumsq + C2v);
                ssum += num * __builtin_amdgcn_rcpf(den);
            }
        }
    }

    // ---- block reduction (4 waves) ----
#pragma unroll
    for (int off = 32; off > 0; off >>= 1)
        ssum += __shfl_down(ssum, off, 64);
    __shared__ float wsum[4];
    if ((tid & 63) == 0) wsum[tid >> 6] = ssum;
    __syncthreads();
    if (tid == 0) {
        int bid = (blockIdx.z * GY + blockIdx.y) * GX + blockIdx.x;
        partial[bid] = wsum[0] + wsum[1] + wsum[2] + wsum[3];
    }
}

__global__ __launch_bounds__(256) void ssim_final(
        const float* __restrict__ partial, float* __restrict__ out) {
    float s = 0.f;
    for (int i = threadIdx.x; i < NPART; i += 256) s += partial[i];
#pragma unroll
    for (int off = 32; off > 0; off >>= 1)
        s += __shfl_down(s, off, 64);
    __shared__ float wsum[4];
    int lane = threadIdx.x & 63, wid = threadIdx.x >> 6;
    if (lane == 0) wsum[wid] = s;
    __syncthreads();
    if (threadIdx.x == 0) {
        float tot = wsum[0] + wsum[1] + wsum[2] + wsum[3];
        out[0] = 1.0f - tot / (float)NEL;
    }
}

extern "C" void kernel_launch(void* const* d_in, const int* in_sizes, int n_in,
                              void* d_out, int out_size, void* d_ws, size_t ws_size,
                              hipStream_t stream) {
    const float* p = (const float*)d_in[0];
    const float* t = (const float*)d_in[1];
    float* out = (float*)d_out;
    float* partial = (float*)d_ws;   // NPART floats

    G7 gw;
    {
        double s = 0.0, sig = 7.0 / 6.0;
        double g[7];
        for (int i = 0; i < 7; ++i) {
            double d = (double)i - 3.0;
            g[i] = exp(-d * d / (2.0 * sig * sig));
            s += g[i];
        }
        for (int i = 0; i < 7; ++i) gw.g[i] = (float)(g[i] / s);
    }

    dim3 grid(GX, GY, NB * NZCH);   // (5, 10, 20) = 1000 blocks
    ssim_fused<<<grid, NTHR, 0, stream>>>(p, t, partial, gw);
    ssim_final<<<1, 256, 0, stream>>>(partial, out);
}

// Round 8
// 128.292 us; speedup vs baseline: 1.1414x; 1.0321x over previous
//
#include <hip/hip_runtime.h>
#include <math.h>

#define DD 160
#define HH 160
#define WW 160
#define NB 2
#define NEL (NB*DD*HH*WW)   // 8,192,000 voxels

#define XT 32               // x outputs per block
#define YT 16               // y outputs per block
#define ZC 16               // z outputs per block
#define NTHR 256
#define NZCH (DD/ZC)        // 10
#define GX (WW/XT)          // 5
#define GY (HH/YT)          // 10
#define NBLK (GX*GY*NB*NZCH)   // 1000 blocks x 4 waves = 4000 waves
#define NPART NBLK

#define HR 22               // halo rows (16 + 6)
#define NJOB (HR*8)         // 176 x-conv jobs (< NTHR)
#define CP 35               // c4 physical pitch in float4 (32 + swizzle)

typedef float v2f __attribute__((ext_vector_type(2)));

struct G7 { float g[7]; };

// Fully fused separable 3D SSIM, v7 = R7 + latency attack:
//  * register PREFETCH of slice s+1's 6 float4 issued right after the
//    barrier, before the y-conv -- global miss latency overlaps C+ring VALU
//    instead of serializing ahead of the next slice's x-conv.
//  * XCD-aware swizzle: flat 1D grid, xcd = flat&7 (round-robin dispatch
//    assumption), work = xcd*125 + flat>>3 -> each XCD covers a contiguous
//    slab; y-halo and z-chunk-halo re-reads hit that XCD's 4MB L2 instead
//    of HBM (R7: FETCH 149MB vs 65.5MB unique).
//  * everything else frozen from R7 (v2f pk-fma, c4 swizzle, dbuf, rings).
__global__ __launch_bounds__(NTHR, 4) void ssim_fused(
        const float* __restrict__ p, const float* __restrict__ t,
        float* __restrict__ partial, G7 gw) {
    const int tid = threadIdx.x;
    const int tx  = tid & 31;            // x output column (phase C)
    const int tyo = tid >> 5;            // 0..7, owns y = 2tyo, 2tyo+1

    // XCD-aware work remap (bijection on [0,1000))
    const int flat = blockIdx.x;
    const int w = (flat & 7) * (NBLK / 8) + (flat >> 3);
    const int bx = w % GX;
    const int by = (w / GX) % GY;
    const int bz = w / (GX * GY);        // 0..19

    const int x0 = bx * XT;
    const int y0 = by * YT;
    const int n  = bz / NZCH;
    const int zs = (bz % NZCH) * ZC;

    __shared__ float4 c4[2][HR][CP];

    // z rings: [y-out][slot], slot5 freshest
    v2f r01[2][6], r23[2][6];
#pragma unroll
    for (int yo = 0; yo < 2; ++yo)
#pragma unroll
        for (int j = 0; j < 6; ++j) {
            r01[yo][j] = (v2f)(0.f);
            r23[yo][j] = (v2f)(0.f);
        }

    const float C1v = 1e-4f, C2v = 9e-4f;
    float ssum = 0.f;
    const int hw = HH * WW;
    const float* pv = p + (size_t)n * DD * hw;
    const float* tv = t + (size_t)n * DD * hw;

    // phase-B job decode (tid < 176): row br, x-group bxg
    const int br = tid >> 3;             // 0..21
    const int bxg = tid & 7;             // 0..7
    const int bgy = y0 + br - 3;
    const bool browok = (unsigned)bgy < (unsigned)HH && tid < NJOB;
    const int cbase = x0 + 4 * bxg - 4;  // first loaded column (4-aligned)
    const int pcr = tx + (tx >> 3);      // C-phase swizzled column

    float4 pfa[3], pfb[3];
    auto prefetch = [&](int sx) {
#pragma unroll
        for (int q = 0; q < 3; ++q) {
            pfa[q] = make_float4(0.f, 0.f, 0.f, 0.f);
            pfb[q] = make_float4(0.f, 0.f, 0.f, 0.f);
        }
        if (browok && sx >= 0 && sx < DD && sx < zs + ZC + 3) {
            const float* prow = pv + (size_t)sx * hw + bgy * WW;
            const float* trow = tv + (size_t)sx * hw + bgy * WW;
#pragma unroll
            for (int q = 0; q < 3; ++q) {
                int c0 = cbase + 4 * q;
                if ((unsigned)c0 < (unsigned)WW) {
                    pfa[q] = *(const float4*)(prow + c0);
                    pfb[q] = *(const float4*)(trow + c0);
                }
            }
        }
    };

    prefetch(zs - 3);

    for (int s = zs - 3; s < zs + ZC + 3; ++s) {
        const int par = s & 1;
        const bool valid = (s >= 0) && (s < DD);   // block-uniform

        if (valid) {
            // ---- B: x-conv from prefetched registers ----
            if (tid < NJOB) {
                v2f s01[4], s23[4];
#pragma unroll
                for (int e = 0; e < 4; ++e) { s01[e] = (v2f)(0.f); s23[e] = (v2f)(0.f); }
#pragma unroll
                for (int q = 0; q < 3; ++q) {
                    const float af[4] = {pfa[q].x, pfa[q].y, pfa[q].z, pfa[q].w};
                    const float bf[4] = {pfb[q].x, pfb[q].y, pfb[q].z, pfb[q].w};
#pragma unroll
                    for (int j = 0; j < 4; ++j) {
                        const int i = 4 * q + j;     // loaded position 0..11
                        v2f pt; pt[0] = af[j]; pt[1] = bf[j];
                        v2f ud; ud[0] = af[j] + bf[j]; ud[1] = af[j] - bf[j];
                        v2f qu = ud * ud;
#pragma unroll
                        for (int e = 0; e < 4; ++e) {
                            const int k = i - e - 1;  // tap index
                            if (k >= 0 && k < 7) {
                                s01[e] = gw.g[k] * pt + s01[e];
                                s23[e] = gw.g[k] * qu + s23[e];
                            }
                        }
                    }
                }
#pragma unroll
                for (int e = 0; e < 4; ++e) {
                    int c = 4 * bxg + e;
                    c4[par][br][c + (c >> 3)] =
                        make_float4(s01[e][0], s01[e][1], s23[e][0], s23[e][1]);
                }
            }
            __syncthreads();   // block-uniform (valid is uniform)
        }

        // ---- issue next slice's global loads NOW (overlap C + ring) ----
        prefetch(s + 1);

        v2f m01[2], m23[2];
#pragma unroll
        for (int yo = 0; yo < 2; ++yo) {
            m01[yo] = (v2f)(0.f);
            m23[yo] = (v2f)(0.f);
        }

        if (valid) {
            // ---- C: y-conv, stream 8 rows for both y-outputs ----
#pragma unroll
            for (int r8 = 0; r8 < 8; ++r8) {
                float4 v = c4[par][2 * tyo + r8][pcr];
                v2f v01; v01[0] = v.x; v01[1] = v.y;
                v2f v23; v23[0] = v.z; v23[1] = v.w;
                if (r8 < 7) {
                    float w2 = gw.g[r8];
                    m01[0] = w2 * v01 + m01[0];
                    m23[0] = w2 * v23 + m23[0];
                }
                if (r8 > 0) {
                    float w2 = gw.g[r8 - 1];
                    m01[1] = w2 * v01 + m01[1];
                    m23[1] = w2 * v23 + m23[1];
                }
            }
            // no trailing barrier: dbuf; WAR fenced by next slice's barrier.
        }

        // ---- z rings: consume slot0, shift+FMA, refill ----
#pragma unroll
        for (int yo = 0; yo < 2; ++yo) {
            v2f v01 = m01[yo], v23 = m23[yo];
            v2f cons01 = gw.g[6] * v01 + r01[yo][0];
            v2f cons23 = gw.g[6] * v23 + r23[yo][0];
#pragma unroll
            for (int j = 0; j < 5; ++j) {
                r01[yo][j] = gw.g[5 - j] * v01 + r01[yo][j + 1];
                r23[yo][j] = gw.g[5 - j] * v23 + r23[yo][j + 1];
            }
            r01[yo][5] = gw.g[0] * v01;
            r23[yo][5] = gw.g[0] * v23;

            if (s >= zs + 3) {   // output z = s-3
                float mu1 = cons01[0], mu2 = cons01[1];
                float Eu  = cons23[0], Ew  = cons23[1];
                float mu12 = mu1 * mu2, mu1sq = mu1 * mu1, mu2sq = mu2 * mu2;
                float sumsq = 0.5f  * (Eu + Ew) - mu1sq - mu2sq; // s1+s2
                float s12   = 0.25f * (Eu - Ew) - mu12;          // sigma12
                float num = (2.f * mu12 + C1v) * (2.f * s12 + C2v);
                float den = (mu1sq + mu2sq + C1v) * (sumsq + C2v);
                ssum += num * __builtin_amdgcn_rcpf(den);
            }
        }
    }

    // ---- block reduction (4 waves) ----
#pragma unroll
    for (int off = 32; off > 0; off >>= 1)
        ssum += __shfl_down(ssum, off, 64);
    __shared__ float wsum[4];
    if ((tid & 63) == 0) wsum[tid >> 6] = ssum;
    __syncthreads();
    if (tid == 0)
        partial[flat] = wsum[0] + wsum[1] + wsum[2] + wsum[3];
}

__global__ __launch_bounds__(256) void ssim_final(
        const float* __restrict__ partial, float* __restrict__ out) {
    float s = 0.f;
    for (int i = threadIdx.x; i < NPART; i += 256) s += partial[i];
#pragma unroll
    for (int off = 32; off > 0; off >>= 1)
        s += __shfl_down(s, off, 64);
    __shared__ float wsum[4];
    int lane = threadIdx.x & 63, wid = threadIdx.x >> 6;
    if (lane == 0) wsum[wid] = s;
    __syncthreads();
    if (threadIdx.x == 0) {
        float tot = wsum[0] + wsum[1] + wsum[2] + wsum[3];
        out[0] = 1.0f - tot / (float)NEL;
    }
}

extern "C" void kernel_launch(void* const* d_in, const int* in_sizes, int n_in,
                              void* d_out, int out_size, void* d_ws, size_t ws_size,
                              hipStream_t stream) {
    const float* p = (const float*)d_in[0];
    const float* t = (const float*)d_in[1];
    float* out = (float*)d_out;
    float* partial = (float*)d_ws;   // NPART floats

    G7 gw;
    {
        double s = 0.0, sig = 7.0 / 6.0;
        double g[7];
        for (int i = 0; i < 7; ++i) {
            double d = (double)i - 3.0;
            g[i] = exp(-d * d / (2.0 * sig * sig));
            s += g[i];
        }
        for (int i = 0; i < 7; ++i) gw.g[i] = (float)(g[i] / s);
    }

    ssim_fused<<<NBLK, NTHR, 0, stream>>>(p, t, partial, gw);
    ssim_final<<<1, 256, 0, stream>>>(partial, out);
}